// Round 1
// baseline (156.888 us; speedup 1.0000x reference)
//
#include <hip/hip_runtime.h>

#define NN 50000
#define KK 16
#define FF 128

__device__ __forceinline__ float wred64(float v) {
  v += __shfl_xor(v, 1);
  v += __shfl_xor(v, 2);
  v += __shfl_xor(v, 4);
  v += __shfl_xor(v, 8);
  v += __shfl_xor(v, 16);
  v += __shfl_xor(v, 32);
  return v;
}

// Fused GAT: per block = 64 nodes.
// Phase A (wave-per-16-nodes): scores = ox@Wa1 + x_k@Wa2, leakyrelu+mask+softmax,
//   xa = ox + sum_k att_k * x_k   -> LDS [f][node] (stride 68)
// Phase B: h' = xa @ W, elu, store.
__global__ __launch_bounds__(256, 4)
void gat_fused(const float* __restrict__ OX, const float* __restrict__ X,
               const int* __restrict__ ADJ, const float* __restrict__ Wm,
               const float* __restrict__ Av, float* __restrict__ out) {
  __shared__ float xs[FF * 68];   // xa, layout [f][node_local], stride 68 (16B-aligned rows)
  __shared__ float wa[256];       // wa1 = W@a1 in [0,128), wa2 = W@a2 in [128,256)

  const int tid = threadIdx.x;
  const int l = tid & 63;
  const int wu = __builtin_amdgcn_readfirstlane(tid >> 6); // wave id, forced SGPR
  const int nb = blockIdx.x * 64;

  // ---- phase 0: Wa1/Wa2 = W @ a1, W @ a2 (per block, W is L2-resident) ----
  {
    const int f = tid & 127, sel = tid >> 7;
    const float4* W4 = (const float4*)(Wm + f * FF);
    const float4* A4 = (const float4*)(Av + sel * FF);
    float s = 0.f;
#pragma unroll
    for (int j = 0; j < 32; ++j) {
      float4 wv = W4[j];
      float4 av = A4[j];
      s += wv.x * av.x + wv.y * av.y + wv.z * av.z + wv.w * av.w;
    }
    wa[tid] = s;
  }
  __syncthreads();

  const float wa1_0 = wa[l], wa1_1 = wa[l + 64];
  const float wa2_0 = wa[128 + l], wa2_1 = wa[192 + l];

  // ---- phase A: each wave processes 16 nodes, x in registers ----
  for (int i = 0; i < 16; ++i) {
    const int nl = wu * 16 + i;
    const int n = nb + nl;
    if (n >= NN) break;                       // wave-uniform
    const float* xp = X + (size_t)n * (KK * FF) + l;
    float x0[KK], x1[KK];
#pragma unroll
    for (int k = 0; k < KK; ++k) {
      x0[k] = xp[k * FF];                     // feature l
      x1[k] = xp[k * FF + 64];                // feature l+64
    }
    const float ox0 = OX[(size_t)n * FF + l];
    const float ox1 = OX[(size_t)n * FF + l + 64];

    const float s0 = wred64(fmaf(ox0, wa1_0, ox1 * wa1_1));  // h@a1 for this node
    float sc[KK];
#pragma unroll
    for (int k = 0; k < KK; ++k)
      sc[k] = wred64(fmaf(x0[k], wa2_0, x1[k] * wa2_1)) + s0;

    const int* adjn = ADJ + n * KK;           // wave-uniform -> scalar loads
    float m = -3.0e38f;
#pragma unroll
    for (int k = 0; k < KK; ++k) {
      const float e = fmaxf(sc[k], 0.2f * sc[k]);   // leaky relu
      sc[k] = (adjn[k] > 0) ? e : -9.0e15f;
      m = fmaxf(m, sc[k]);
    }
    float ssum = 0.f;
#pragma unroll
    for (int k = 0; k < KK; ++k) {
      sc[k] = __expf(sc[k] - m);
      ssum += sc[k];
    }
    const float inv = 1.0f / ssum;

    float xa0 = ox0, xa1 = ox1;
#pragma unroll
    for (int k = 0; k < KK; ++k) {
      const float av = sc[k] * inv;
      xa0 = fmaf(av, x0[k], xa0);
      xa1 = fmaf(av, x1[k], xa1);
    }
    xs[l * 68 + nl] = xa0;
    xs[(l + 64) * 68 + nl] = xa1;
  }
  __syncthreads();

  // ---- phase B: out[n, f] = elu( sum_f' xa[n, f'] * W[f', f] ) ----
  // wave wu handles nodes [16wu, 16wu+16); lane l handles features l and l+64.
  float acc0[16], acc1[16];
#pragma unroll
  for (int i = 0; i < 16; ++i) { acc0[i] = 0.f; acc1[i] = 0.f; }

  const float* xrow_base = xs + 16 * wu;
#pragma unroll 2
  for (int fp = 0; fp < FF; ++fp) {
    const float w0 = Wm[fp * FF + l];         // coalesced, L1/L2-resident
    const float w1 = Wm[fp * FF + l + 64];
    const float4* xr = (const float4*)(xrow_base + fp * 68);  // same addr all lanes -> broadcast
    const float4 q0 = xr[0], q1 = xr[1], q2 = xr[2], q3 = xr[3];
    const float xv[16] = {q0.x, q0.y, q0.z, q0.w, q1.x, q1.y, q1.z, q1.w,
                          q2.x, q2.y, q2.z, q2.w, q3.x, q3.y, q3.z, q3.w};
#pragma unroll
    for (int i = 0; i < 16; ++i) {
      acc0[i] = fmaf(xv[i], w0, acc0[i]);
      acc1[i] = fmaf(xv[i], w1, acc1[i]);
    }
  }

#pragma unroll
  for (int i = 0; i < 16; ++i) {
    const int n2 = nb + 16 * wu + i;
    if (n2 < NN) {
      float v0 = acc0[i];
      float v1 = acc1[i];
      v0 = v0 > 0.f ? v0 : expm1f(v0);        // elu, alpha=1
      v1 = v1 > 0.f ? v1 : expm1f(v1);
      out[(size_t)n2 * FF + l] = v0;
      out[(size_t)n2 * FF + l + 64] = v1;
    }
  }
}

extern "C" void kernel_launch(void* const* d_in, const int* in_sizes, int n_in,
                              void* d_out, int out_size, void* d_ws, size_t ws_size,
                              hipStream_t stream) {
  const float* OX  = (const float*)d_in[0];   // orignal_x (N,F)
  const float* X   = (const float*)d_in[1];   // x (N,K,F)
  const int*   ADJ = (const int*)d_in[2];     // adj (N,K)
  const float* Wm  = (const float*)d_in[3];   // W (F,F)
  const float* Av  = (const float*)d_in[4];   // a (2F,1)
  float* out = (float*)d_out;

  const int blocks = (NN + 63) / 64;          // 782
  gat_fused<<<blocks, 256, 0, stream>>>(OX, X, ADJ, Wm, Av, out);
}

// Round 2
// 135.322 us; speedup vs baseline: 1.1594x; 1.1594x over previous
//
#include <hip/hip_runtime.h>

#define NN 50000
#define KK 16
#define FF 128
#define NB 32   // nodes per block
#define NW 8    // nodes per wave
#define NEGI -9.0e15f

__global__ __launch_bounds__(256, 4)
void gat_fused(const float* __restrict__ OX, const float* __restrict__ X,
               const int* __restrict__ ADJ, const float* __restrict__ Wm,
               const float* __restrict__ Av, float* __restrict__ out) {
  // xa staged as [feature_quad q][local node nl][4 floats], row stride 132 floats
  __shared__ float xs[32 * 132];
  __shared__ float wa[256];   // [0,128)=W@a1, [128,256)=W@a2

  const int tid  = threadIdx.x;
  const int l    = tid & 63;
  const int j    = l & 31;          // feature-quad owned: features 4j..4j+3
  const int half = l >> 5;          // k parity owned in phase A
  const int wu   = __builtin_amdgcn_readfirstlane(tid >> 6);
  const int nb   = blockIdx.x * NB;

  // ---- phase 0: wa1/wa2 = W @ a1, W @ a2 (W is L2-resident) ----
  {
    const int f = tid & 127, sel = tid >> 7;
    const float4* W4 = (const float4*)(Wm + f * FF);
    const float4* A4 = (const float4*)(Av + sel * FF);
    float s = 0.f;
#pragma unroll
    for (int t = 0; t < 32; ++t) {
      float4 wv = W4[t], av = A4[t];
      s += wv.x * av.x + wv.y * av.y + wv.z * av.z + wv.w * av.w;
    }
    wa[tid] = s;
  }
  __syncthreads();

  const float4 w1 = *(const float4*)&wa[4 * j];
  const float4 w2 = *(const float4*)&wa[FF + 4 * j];

  // ---- phase A: 8 nodes per wave; lane layout = natural coalesced float4 ----
  // xv[t] holds flat floats 256t+4l..+3 of X[n] => k = 2t+half, f = 4j..4j+3
  for (int i = 0; i < NW; ++i) {
    const int nl = wu * NW + i;
    const int n  = nb + nl;
    if (n >= NN) break;                         // wave-uniform

    const float4* xp4 = (const float4*)(X + (size_t)n * (KK * FF));
    float4 xv[8];
#pragma unroll
    for (int t = 0; t < 8; ++t) xv[t] = xp4[t * 64 + l];
    const float4 oxv = ((const float4*)(OX + (size_t)n * FF))[j];

    // s0 = (ox @ W) @ a1 : 32-lane butterfly (halves are identical copies)
    float s0 = fmaf(oxv.x, w1.x, fmaf(oxv.y, w1.y, fmaf(oxv.z, w1.z, oxv.w * w1.w)));
    s0 += __shfl_xor(s0, 1);  s0 += __shfl_xor(s0, 2);  s0 += __shfl_xor(s0, 4);
    s0 += __shfl_xor(s0, 8);  s0 += __shfl_xor(s0, 16);

    // per-k scores: half h owns k=2t+h
    float sc[8];
#pragma unroll
    for (int t = 0; t < 8; ++t) {
      float p = fmaf(xv[t].x, w2.x, fmaf(xv[t].y, w2.y, fmaf(xv[t].z, w2.z, xv[t].w * w2.w)));
      p += __shfl_xor(p, 1);  p += __shfl_xor(p, 2);  p += __shfl_xor(p, 4);
      p += __shfl_xor(p, 8);  p += __shfl_xor(p, 16);
      sc[t] = p;
    }
    float sco[8];
#pragma unroll
    for (int t = 0; t < 8; ++t) sco[t] = __shfl_xor(sc[t], 32);  // k = 2t+(1-half)

    const int* adjn = ADJ + n * KK;             // n uniform -> scalar loads
    float eo[8], et[8];
    float m = -3.0e38f;
#pragma unroll
    for (int t = 0; t < 8; ++t) {
      float so = sc[t] + s0;
      float sn = sco[t] + s0;
      so = fmaxf(so, 0.2f * so);
      sn = fmaxf(sn, 0.2f * sn);
      const int a0 = adjn[2 * t], a1 = adjn[2 * t + 1];
      const int ao = half ? a1 : a0;            // adj for own k
      const int an = half ? a0 : a1;            // adj for other k
      eo[t] = (ao > 0) ? so : NEGI;
      et[t] = (an > 0) ? sn : NEGI;
      m = fmaxf(m, fmaxf(eo[t], et[t]));
    }
    float ssum = 0.f;
    float aw[8];
#pragma unroll
    for (int t = 0; t < 8; ++t) {
      aw[t] = __expf(eo[t] - m);
      ssum += aw[t] + __expf(et[t] - m);
    }
    const float inv = 1.0f / ssum;

    float4 pacc = {0.f, 0.f, 0.f, 0.f};
#pragma unroll
    for (int t = 0; t < 8; ++t) {
      pacc.x = fmaf(aw[t], xv[t].x, pacc.x);
      pacc.y = fmaf(aw[t], xv[t].y, pacc.y);
      pacc.z = fmaf(aw[t], xv[t].z, pacc.z);
      pacc.w = fmaf(aw[t], xv[t].w, pacc.w);
    }
    // combine k-parities across halves; both halves end identical
    float4 xa;
    xa.x = fmaf(inv, pacc.x + __shfl_xor(pacc.x, 32), oxv.x);
    xa.y = fmaf(inv, pacc.y + __shfl_xor(pacc.y, 32), oxv.y);
    xa.z = fmaf(inv, pacc.z + __shfl_xor(pacc.z, 32), oxv.z);
    xa.w = fmaf(inv, pacc.w + __shfl_xor(pacc.w, 32), oxv.w);

    if (half == 0)
      *(float4*)&xs[j * 132 + nl * 4] = xa;     // ds_write_b128, ~4-way
  }
  __syncthreads();

  // ---- phase B: out[n,:] = elu( xa[n,:] @ W ); wave handles 8 nodes ----
  float acc0[NW], acc1[NW];
#pragma unroll
  for (int i = 0; i < NW; ++i) { acc0[i] = 0.f; acc1[i] = 0.f; }

  const int nbase = NW * wu;
#pragma unroll 4
  for (int q = 0; q < 32; ++q) {
    const float* wr = Wm + (size_t)(4 * q) * FF;
    const float w00 = wr[l],            w01 = wr[FF + l];
    const float w02 = wr[2 * FF + l],   w03 = wr[3 * FF + l];
    const float w10 = wr[64 + l],       w11 = wr[FF + 64 + l];
    const float w12 = wr[2 * FF + 64 + l], w13 = wr[3 * FF + 64 + l];
    const float4* xq = (const float4*)&xs[q * 132 + nbase * 4];
#pragma unroll
    for (int i = 0; i < NW; ++i) {
      const float4 xv4 = xq[i];                 // broadcast ds_read_b128
      acc0[i] = fmaf(xv4.x, w00, fmaf(xv4.y, w01, fmaf(xv4.z, w02, fmaf(xv4.w, w03, acc0[i]))));
      acc1[i] = fmaf(xv4.x, w10, fmaf(xv4.y, w11, fmaf(xv4.z, w12, fmaf(xv4.w, w13, acc1[i]))));
    }
  }

#pragma unroll
  for (int i = 0; i < NW; ++i) {
    const int n2 = nb + nbase + i;
    if (n2 < NN) {
      float v0 = acc0[i], v1 = acc1[i];
      v0 = v0 > 0.f ? v0 : expm1f(v0);
      v1 = v1 > 0.f ? v1 : expm1f(v1);
      out[(size_t)n2 * FF + l] = v0;
      out[(size_t)n2 * FF + l + 64] = v1;
    }
  }
}

extern "C" void kernel_launch(void* const* d_in, const int* in_sizes, int n_in,
                              void* d_out, int out_size, void* d_ws, size_t ws_size,
                              hipStream_t stream) {
  const float* OX  = (const float*)d_in[0];
  const float* X   = (const float*)d_in[1];
  const int*   ADJ = (const int*)d_in[2];
  const float* Wm  = (const float*)d_in[3];
  const float* Av  = (const float*)d_in[4];
  float* out = (float*)d_out;

  const int blocks = (NN + NB - 1) / NB;   // 1563
  gat_fused<<<blocks, 256, 0, stream>>>(OX, X, ADJ, Wm, Av, out);
}

// Round 4
// 134.916 us; speedup vs baseline: 1.1629x; 1.0030x over previous
//
#include <hip/hip_runtime.h>

#define NN 50000
#define KK 16
#define FF 128
#define NB 32   // nodes per block
#define NW 8    // nodes per wave
#define NEGI -9.0e15f

template <int CTRL>
__device__ __forceinline__ float dpp_add(float v) {
  int s = __builtin_amdgcn_mov_dpp(__float_as_int(v), CTRL, 0xF, 0xF, true);
  return v + __int_as_float(s);
}
template <int PAT>
__device__ __forceinline__ float swz_add(float v) {
  int s = __builtin_amdgcn_ds_swizzle(__float_as_int(v), PAT);
  return v + __int_as_float(s);
}
// sum across each 32-lane half (halves independent)
__device__ __forceinline__ float red32(float v) {
  v = dpp_add<0xB1>(v);    // quad_perm [1,0,3,2] : + lane^1
  v = dpp_add<0x4E>(v);    // quad_perm [2,3,0,1] : + lane^2
  v = dpp_add<0x141>(v);   // row_half_mirror     : + lane^4
  v = dpp_add<0x140>(v);   // row_mirror          : + lane^8
  v = swz_add<0x401F>(v);  // ds_swizzle xor16    : + lane^16
  return v;
}
__device__ __forceinline__ float dot4(float4 a, float4 b) {
  return fmaf(a.x, b.x, fmaf(a.y, b.y, fmaf(a.z, b.z, a.w * b.w)));
}

// pre-kernel: wa[0:128)=W@a1, wa[128:256)=W@a2  -> d_ws
__global__ void gat_wa(const float* __restrict__ Wm, const float* __restrict__ Av,
                       float* __restrict__ wa_out) {
  const int t = threadIdx.x;            // 256 threads
  const int f = t & 127, sel = t >> 7;
  const float4* W4 = (const float4*)(Wm + f * FF);
  const float4* A4 = (const float4*)(Av + sel * FF);
  float s = 0.f;
#pragma unroll
  for (int u = 0; u < 32; ++u) {
    float4 wv = W4[u], av = A4[u];
    s += wv.x * av.x + wv.y * av.y + wv.z * av.z + wv.w * av.w;
  }
  wa_out[t] = s;
}

// main: barrier-free, waves independent. Per wave: 8 nodes, A then B.
__global__ __launch_bounds__(256, 4)
void gat_fused(const float* __restrict__ OX, const float* __restrict__ X,
               const int* __restrict__ ADJ, const float* __restrict__ WA,
               const float* __restrict__ Wm, float* __restrict__ out) {
  // per-wave xa slice: [quad q 0..31][node 0..7][4], row stride 36 floats
  __shared__ float xs[4 * 32 * 36];

  const int tid  = threadIdx.x;
  const int l    = tid & 63;
  const int j    = l & 31;             // feature quad: features 4j..4j+3
  const int half = l >> 5;             // k parity in phase A
  const int wu   = __builtin_amdgcn_readfirstlane(tid >> 6);
  const int nbase = blockIdx.x * NB + wu * NW;
  float* xsw = xs + wu * (32 * 36);

  const float4 w1 = ((const float4*)WA)[j];        // (W@a1) quad
  const float4 w2 = ((const float4*)WA)[32 + j];   // (W@a2) quad

  const int limit = (NN - nbase < NW) ? (NN - nbase) : NW;  // may be <=0

  auto PRELOAD = [&](int i, float4* xv, float4& ox) {
    const int n = nbase + i;
    const float4* xp4 = (const float4*)(X + (size_t)n * (KK * FF));
#pragma unroll
    for (int t = 0; t < 8; ++t) xv[t] = xp4[t * 64 + l];
    ox = ((const float4*)(OX + (size_t)n * FF))[j];
  };

  auto PROCESS = [&](int i, const float4* xv, float4 ox) {
    const int n = nbase + i;
    const int* adjp = ADJ + n * KK;
    // own-half adjacency: k = 2t + half
    int adv[8];
#pragma unroll
    for (int t = 0; t < 8; ++t) adv[t] = adjp[2 * t + half];

    const float s0 = red32(dot4(ox, w1));
    float e[8];
#pragma unroll
    for (int t = 0; t < 8; ++t) e[t] = red32(dot4(xv[t], w2)) + s0;

    float m = -3.0e38f;
#pragma unroll
    for (int t = 0; t < 8; ++t) {
      float v = e[t];
      v = fmaxf(v, 0.2f * v);                    // leaky relu
      e[t] = (adv[t] > 0) ? v : NEGI;
      m = fmaxf(m, e[t]);
    }
    m = fmaxf(m, __shfl_xor(m, 32));             // global max over 16 k

    float ss = 0.f;
    float4 pacc = {0.f, 0.f, 0.f, 0.f};
#pragma unroll
    for (int t = 0; t < 8; ++t) {
      const float w = __expf(e[t] - m);
      ss += w;
      pacc.x = fmaf(w, xv[t].x, pacc.x);
      pacc.y = fmaf(w, xv[t].y, pacc.y);
      pacc.z = fmaf(w, xv[t].z, pacc.z);
      pacc.w = fmaf(w, xv[t].w, pacc.w);
    }
    ss += __shfl_xor(ss, 32);
    pacc.x += __shfl_xor(pacc.x, 32);
    pacc.y += __shfl_xor(pacc.y, 32);
    pacc.z += __shfl_xor(pacc.z, 32);
    pacc.w += __shfl_xor(pacc.w, 32);
    const float inv = 1.0f / ss;

    float4 xa;
    xa.x = fmaf(inv, pacc.x, ox.x);
    xa.y = fmaf(inv, pacc.y, ox.y);
    xa.z = fmaf(inv, pacc.z, ox.z);
    xa.w = fmaf(inv, pacc.w, ox.w);

    if (half == 0)
      *(float4*)&xsw[j * 36 + i * 4] = xa;       // ds_write_b128
  };

  // ---- phase A: 2-node software pipeline ----
  float4 xva[8], xvb[8], oxa, oxb;
  if (limit > 0) PRELOAD(0, xva, oxa);
  for (int i = 0; i < limit; i += 2) {
    if (i + 1 < limit) PRELOAD(i + 1, xvb, oxb);
    PROCESS(i, xva, oxa);
    if (i + 2 < limit) PRELOAD(i + 2, xva, oxa);
    if (i + 1 < limit) PROCESS(i + 1, xvb, oxb);
  }

  // ---- phase B: out[n, 2l..2l+1] = elu( xa[n,:] @ W[:, 2l..2l+1] ) ----
  float2 acc[NW];
#pragma unroll
  for (int i = 0; i < NW; ++i) { acc[i].x = 0.f; acc[i].y = 0.f; }

#pragma unroll 4
  for (int q = 0; q < 32; ++q) {
    const float* wr = Wm + (size_t)(4 * q) * FF;
    const float2 wv0 = ((const float2*)(wr))[l];
    const float2 wv1 = ((const float2*)(wr + FF))[l];
    const float2 wv2 = ((const float2*)(wr + 2 * FF))[l];
    const float2 wv3 = ((const float2*)(wr + 3 * FF))[l];
#pragma unroll
    for (int i = 0; i < NW; ++i) {
      const float4 xa4 = *(const float4*)&xsw[q * 36 + i * 4];  // broadcast
      acc[i].x = fmaf(xa4.x, wv0.x, fmaf(xa4.y, wv1.x, fmaf(xa4.z, wv2.x, fmaf(xa4.w, wv3.x, acc[i].x))));
      acc[i].y = fmaf(xa4.x, wv0.y, fmaf(xa4.y, wv1.y, fmaf(xa4.z, wv2.y, fmaf(xa4.w, wv3.y, acc[i].y))));
    }
  }

#pragma unroll
  for (int i = 0; i < NW; ++i) {
    const int n2 = nbase + i;
    if (n2 < NN) {
      float2 st;
      st.x = acc[i].x > 0.f ? acc[i].x : (__expf(acc[i].x) - 1.0f);
      st.y = acc[i].y > 0.f ? acc[i].y : (__expf(acc[i].y) - 1.0f);
      ((float2*)(out + (size_t)n2 * FF))[l] = st;
    }
  }
}

extern "C" void kernel_launch(void* const* d_in, const int* in_sizes, int n_in,
                              void* d_out, int out_size, void* d_ws, size_t ws_size,
                              hipStream_t stream) {
  const float* OX  = (const float*)d_in[0];
  const float* X   = (const float*)d_in[1];
  const int*   ADJ = (const int*)d_in[2];
  const float* Wm  = (const float*)d_in[3];
  const float* Av  = (const float*)d_in[4];
  float* out = (float*)d_out;
  float* wa  = (float*)d_ws;

  gat_wa<<<1, 256, 0, stream>>>(Wm, Av, wa);
  const int blocks = (NN + NB - 1) / NB;   // 1563
  gat_fused<<<blocks, 256, 0, stream>>>(OX, X, ADJ, wa, Wm, out);
}